// Round 3
// baseline (108.136 us; speedup 1.0000x reference)
//
#include <hip/hip_runtime.h>

#define B_ 64
#define N_ 768
#define F_ 256
#define P_ 64
#define T_ 16
#define K_ 3
#define L_ 12           // N_/P_
#define CH_ 3           // column chunks per (b,l) adj tile
#define CCOLS 256       // columns per chunk (= 4 m-blocks of 64)
#define TSTR 260        // tmp row stride in dwords: 1040 B, 16B-aligned, ==4 mod 32 banks

// Fused kernel, grid = 768*4 blocks of 256 threads.
//   blk%4==3 : conv role (pooled_x), idx = blk>>2          (768 blocks)
//   else     : adj role (pooled_adj), one (b,l,chunk) each (2304 blocks)
// adj role: Phase A computes tmp[t][c] = sum_p s[t,p]*adj[p][c] for 256 cols;
// wave w owns t=4w..4w+3 both producing AND consuming tmp -> no block barrier,
// only lgkmcnt drain + sched fence (intra-wave LDS exchange).
__global__ __launch_bounds__(256) void fused_pool_kernel(
    const float* __restrict__ x, const float* __restrict__ adj,
    const float* __restrict__ conv_w, const float* __restrict__ conv_b,
    const float* __restrict__ re_param,
    float* __restrict__ out_x, float* __restrict__ out_adj)
{
    __shared__ float sT[P_][T_];     // 4 KB: sT[p][t] = s[t,p]
    __shared__ float tmp[T_][TSTR];  // 16.25 KB

    const int blk = blockIdx.x;
    const int tid = threadIdx.x;

    if ((blk & 3) == 3) {
        // ---------------- pooled_x ----------------
        const int idx = blk >> 2;
        const int b = idx / L_, l = idx % L_;
        const int f = tid;
        const float* xb = x + (size_t)b * N_ * F_ + (size_t)l * F_;

        float acc[T_];
        #pragma unroll
        for (int t = 0; t < T_; ++t) acc[t] = conv_b[t];

        for (int p = 0; p < P_; ++p) {
            const float* row = xb + (size_t)p * (L_ * F_);
            const float xm = (f > 0)      ? row[f - 1] : 0.f;
            const float x0 = row[f];
            const float xp = (f < F_ - 1) ? row[f + 1] : 0.f;
            const float* wp = conv_w + p * K_;   // thread-uniform -> scalar loads
            #pragma unroll
            for (int t = 0; t < T_; ++t) {
                const float w0 = wp[t * (P_ * K_) + 0];
                const float w1 = wp[t * (P_ * K_) + 1];
                const float w2 = wp[t * (P_ * K_) + 2];
                acc[t] = fmaf(xm, w0, fmaf(x0, w1, fmaf(xp, w2, acc[t])));
            }
        }
        float* ob = out_x + (size_t)b * (T_ * L_) * F_ + f;
        #pragma unroll
        for (int t = 0; t < T_; ++t)
            ob[(size_t)(t * L_ + l) * F_] = acc[t];
        return;
    }

    // ---------------- pooled_adj (one column chunk) ----------------
    const int aidx = (blk >> 2) * CH_ + (blk & 3);       // 0..2303
    const int b = aidx / (L_ * CH_);
    const int rem = aidx % (L_ * CH_);
    const int l = rem / CH_;
    const int i = rem % CH_;                             // column chunk 0..2

    // s[t,p] = sum_k conv_w[t,p,k] * re_param[k]
    const float r0 = re_param[0], r1 = re_param[1], r2 = re_param[2];
    for (int j = tid; j < P_ * T_; j += 256) {
        const int p = j >> 4, t = j & 15;
        const float* wv = conv_w + (size_t)t * (P_ * K_) + (size_t)p * K_;
        sT[p][t] = wv[0] * r0 + wv[1] * r1 + wv[2] * r2;
    }
    __syncthreads();

    // Phase A: tmp[4w+j][4ct+r] accumulated in registers.
    const int w  = tid >> 6;
    const int ct = tid & 63;

    float acc[4][4];
    #pragma unroll
    for (int j = 0; j < 4; ++j)
        #pragma unroll
        for (int r = 0; r < 4; ++r) acc[j][r] = 0.f;

    const float* ab = adj + (size_t)b * N_ * N_ + (size_t)(l * P_) * N_
                          + (size_t)i * CCOLS + 4 * ct;
    #pragma unroll 4
    for (int p = 0; p < P_; ++p) {
        const float4 a  = *(const float4*)(ab + (size_t)p * N_);
        const float4 sv = *(const float4*)&sT[p][4 * w];   // wave-uniform b128 broadcast
        acc[0][0] = fmaf(sv.x, a.x, acc[0][0]);
        acc[0][1] = fmaf(sv.x, a.y, acc[0][1]);
        acc[0][2] = fmaf(sv.x, a.z, acc[0][2]);
        acc[0][3] = fmaf(sv.x, a.w, acc[0][3]);
        acc[1][0] = fmaf(sv.y, a.x, acc[1][0]);
        acc[1][1] = fmaf(sv.y, a.y, acc[1][1]);
        acc[1][2] = fmaf(sv.y, a.z, acc[1][2]);
        acc[1][3] = fmaf(sv.y, a.w, acc[1][3]);
        acc[2][0] = fmaf(sv.z, a.x, acc[2][0]);
        acc[2][1] = fmaf(sv.z, a.y, acc[2][1]);
        acc[2][2] = fmaf(sv.z, a.z, acc[2][2]);
        acc[2][3] = fmaf(sv.z, a.w, acc[2][3]);
        acc[3][0] = fmaf(sv.w, a.x, acc[3][0]);
        acc[3][1] = fmaf(sv.w, a.y, acc[3][1]);
        acc[3][2] = fmaf(sv.w, a.z, acc[3][2]);
        acc[3][3] = fmaf(sv.w, a.w, acc[3][3]);
    }

    #pragma unroll
    for (int j = 0; j < 4; ++j) {
        float4 v;
        v.x = acc[j][0]; v.y = acc[j][1]; v.z = acc[j][2]; v.w = acc[j][3];
        *(float4*)&tmp[4 * w + j][4 * ct] = v;
    }
    // A->B dependency is intra-wave (wave w wrote rows 4w..4w+3, and its own
    // threads t=tid>>4 in [4w,4w+4) read them). Drain LDS writes; fence the
    // compiler so the reads below cannot hoist above this point.
    asm volatile("s_waitcnt lgkmcnt(0)" ::: "memory");
    __builtin_amdgcn_sched_barrier(0);

    // Phase B: out[b, l*T+t, (4i+mi)*T+u] = sum_q tmp[t][mi*64+q] * sT[q][u]
    const int t = tid >> 4, u = tid & 15;
    float sum[4] = {0.f, 0.f, 0.f, 0.f};

    for (int q4 = 0; q4 < P_; q4 += 4) {
        const float s0 = sT[q4 + 0][u];
        const float s1 = sT[q4 + 1][u];
        const float s2 = sT[q4 + 2][u];
        const float s3 = sT[q4 + 3][u];
        #pragma unroll
        for (int mi = 0; mi < 4; ++mi) {
            const float4 tv = *(const float4*)&tmp[t][mi * P_ + q4];
            sum[mi] = fmaf(tv.x, s0, fmaf(tv.y, s1, fmaf(tv.z, s2, fmaf(tv.w, s3, sum[mi]))));
        }
    }

    float* ob = out_adj + (size_t)b * (L_ * T_) * (L_ * T_)
                        + (size_t)(l * T_ + t) * (L_ * T_)
                        + (size_t)(4 * i) * T_ + u;
    #pragma unroll
    for (int mi = 0; mi < 4; ++mi)
        ob[mi * T_] = sum[mi];
}

// ---------------------------------------------------------------------------
extern "C" void kernel_launch(void* const* d_in, const int* in_sizes, int n_in,
                              void* d_out, int out_size, void* d_ws, size_t ws_size,
                              hipStream_t stream) {
    (void)in_sizes; (void)n_in; (void)out_size; (void)d_ws; (void)ws_size;
    const float* x        = (const float*)d_in[0];
    const float* adj      = (const float*)d_in[1];
    const float* conv_w   = (const float*)d_in[2];
    const float* conv_b   = (const float*)d_in[3];
    const float* re_param = (const float*)d_in[4];

    float* pooled_x   = (float*)d_out;
    float* pooled_adj = (float*)d_out + (size_t)B_ * (T_ * L_) * F_;

    fused_pool_kernel<<<B_ * L_ * 4, 256, 0, stream>>>(
        x, adj, conv_w, conv_b, re_param, pooled_x, pooled_adj);
}

// Round 4
// 87.136 us; speedup vs baseline: 1.2410x; 1.2410x over previous
//
#include <hip/hip_runtime.h>

#define B_ 64
#define N_ 768
#define F_ 256
#define P_ 64
#define T_ 16
#define K_ 3
#define L_ 12           // N_/P_
#define TSTR 772        // tmp row stride (dwords): 768+4; 3088 B, 16B-aligned, ==4 mod 32 banks

// Fused kernel, grid = 1536 blocks of 256 threads.
// XCD-aware swizzle groups all 24 blocks of one batch b on one XCD.
// role: r<12 -> pooled_adj (l=r), r>=12 -> pooled_x (l=r-12).
__global__ __launch_bounds__(256) void fused_pool_kernel(
    const float* __restrict__ x, const float* __restrict__ adj,
    const float* __restrict__ conv_w, const float* __restrict__ conv_b,
    const float* __restrict__ re_param,
    float* __restrict__ out_x, float* __restrict__ out_adj)
{
    __shared__ float sT[P_][T_];     // 4 KB: sT[p][t] = s[t,p]
    __shared__ float tmp[T_][TSTR];  // 49.4 KB

    // bijective XCD swizzle: 1536 = 8 XCDs * 192
    const int g  = blockIdx.x;
    const int Lg = (g & 7) * 192 + (g >> 3);
    const int b  = Lg / 24;
    const int r  = Lg % 24;
    const int tid = threadIdx.x;

    if (r >= L_) {
        // ---------------- pooled_x ----------------
        const int l = r - L_;
        const int f = tid;
        const float* xb = x + (size_t)b * N_ * F_ + (size_t)l * F_;

        float acc[T_];
        #pragma unroll
        for (int t = 0; t < T_; ++t) acc[t] = conv_b[t];

        for (int p0 = 0; p0 < P_; p0 += 2) {
            float xm[2], x0[2], xp[2];
            #pragma unroll
            for (int rr = 0; rr < 2; ++rr) {
                const float* row = xb + (size_t)(p0 + rr) * (L_ * F_);
                xm[rr] = (f > 0)      ? row[f - 1] : 0.f;
                x0[rr] = row[f];
                xp[rr] = (f < F_ - 1) ? row[f + 1] : 0.f;
            }
            #pragma unroll
            for (int rr = 0; rr < 2; ++rr) {
                const float* wp = conv_w + (p0 + rr) * K_;  // thread-uniform
                #pragma unroll
                for (int t = 0; t < T_; ++t) {
                    const float w0 = wp[t * (P_ * K_) + 0];
                    const float w1 = wp[t * (P_ * K_) + 1];
                    const float w2 = wp[t * (P_ * K_) + 2];
                    acc[t] = fmaf(xm[rr], w0, fmaf(x0[rr], w1, fmaf(xp[rr], w2, acc[t])));
                }
            }
        }
        float* ob = out_x + (size_t)b * (T_ * L_) * F_ + f;
        #pragma unroll
        for (int t = 0; t < T_; ++t)
            ob[(size_t)(t * L_ + l) * F_] = acc[t];
        return;
    }

    // ---------------- pooled_adj ----------------
    const int l = r;

    // s[t,p] = sum_k conv_w[t,p,k] * re_param[k];  sT[p][t] so 4 t's = one b128
    const float r0 = re_param[0], r1 = re_param[1], r2 = re_param[2];
    for (int j = tid; j < P_ * T_; j += 256) {
        const int p = j >> 4, t = j & 15;
        const float* wv = conv_w + (size_t)t * (P_ * K_) + (size_t)p * K_;
        sT[p][t] = wv[0] * r0 + wv[1] * r1 + wv[2] * r2;
    }
    __syncthreads();

    // Phase A: tmp[t][c] = sum_p sT[p][t]*adj[b, l*64+p, c].
    // Thread owns cols {tid, tid+256, tid+512} — each adj element loaded ONCE
    // per block. 8-row batches: 24 independent scalar loads in flight.
    float acc[T_][3];
    #pragma unroll
    for (int t = 0; t < T_; ++t)
        #pragma unroll
        for (int c = 0; c < 3; ++c) acc[t][c] = 0.f;

    const float* ab = adj + (size_t)b * N_ * N_ + (size_t)(l * P_) * N_ + tid;
    for (int p0 = 0; p0 < P_; p0 += 8) {
        float a[8][3];
        #pragma unroll
        for (int rr = 0; rr < 8; ++rr) {
            const float* row = ab + (size_t)(p0 + rr) * N_;
            a[rr][0] = row[0];
            a[rr][1] = row[256];
            a[rr][2] = row[512];
        }
        #pragma unroll
        for (int rr = 0; rr < 8; ++rr) {
            #pragma unroll
            for (int j = 0; j < 4; ++j) {
                const float4 sv = *(const float4*)&sT[p0 + rr][4 * j];  // b128 broadcast
                acc[4*j+0][0] = fmaf(sv.x, a[rr][0], acc[4*j+0][0]);
                acc[4*j+0][1] = fmaf(sv.x, a[rr][1], acc[4*j+0][1]);
                acc[4*j+0][2] = fmaf(sv.x, a[rr][2], acc[4*j+0][2]);
                acc[4*j+1][0] = fmaf(sv.y, a[rr][0], acc[4*j+1][0]);
                acc[4*j+1][1] = fmaf(sv.y, a[rr][1], acc[4*j+1][1]);
                acc[4*j+1][2] = fmaf(sv.y, a[rr][2], acc[4*j+1][2]);
                acc[4*j+2][0] = fmaf(sv.z, a[rr][0], acc[4*j+2][0]);
                acc[4*j+2][1] = fmaf(sv.z, a[rr][1], acc[4*j+2][1]);
                acc[4*j+2][2] = fmaf(sv.z, a[rr][2], acc[4*j+2][2]);
                acc[4*j+3][0] = fmaf(sv.w, a[rr][0], acc[4*j+3][0]);
                acc[4*j+3][1] = fmaf(sv.w, a[rr][1], acc[4*j+3][1]);
                acc[4*j+3][2] = fmaf(sv.w, a[rr][2], acc[4*j+3][2]);
            }
        }
    }
    #pragma unroll
    for (int t = 0; t < T_; ++t) {
        tmp[t][tid]       = acc[t][0];
        tmp[t][tid + 256] = acc[t][1];
        tmp[t][tid + 512] = acc[t][2];
    }
    __syncthreads();

    // Phase B: out[b, l*T+t, m*T+u] = sum_q tmp[t][m*64+q] * sT[q][u]
    const int t = tid >> 4, u = tid & 15;
    float sum[L_];
    #pragma unroll
    for (int m = 0; m < L_; ++m) sum[m] = 0.f;

    for (int q4 = 0; q4 < P_; q4 += 4) {
        const float s0 = sT[q4 + 0][u];
        const float s1 = sT[q4 + 1][u];
        const float s2 = sT[q4 + 2][u];
        const float s3 = sT[q4 + 3][u];
        #pragma unroll
        for (int m = 0; m < L_; ++m) {
            const float4 tv = *(const float4*)&tmp[t][m * P_ + q4];  // broadcast per t-group
            sum[m] = fmaf(tv.x, s0, fmaf(tv.y, s1, fmaf(tv.z, s2, fmaf(tv.w, s3, sum[m]))));
        }
    }

    float* ob = out_adj + (size_t)b * (L_ * T_) * (L_ * T_)
                        + (size_t)(l * T_ + t) * (L_ * T_) + u;
    #pragma unroll
    for (int m = 0; m < L_; ++m)
        ob[m * T_] = sum[m];
}

// ---------------------------------------------------------------------------
extern "C" void kernel_launch(void* const* d_in, const int* in_sizes, int n_in,
                              void* d_out, int out_size, void* d_ws, size_t ws_size,
                              hipStream_t stream) {
    (void)in_sizes; (void)n_in; (void)out_size; (void)d_ws; (void)ws_size;
    const float* x        = (const float*)d_in[0];
    const float* adj      = (const float*)d_in[1];
    const float* conv_w   = (const float*)d_in[2];
    const float* conv_b   = (const float*)d_in[3];
    const float* re_param = (const float*)d_in[4];

    float* pooled_x   = (float*)d_out;
    float* pooled_adj = (float*)d_out + (size_t)B_ * (T_ * L_) * F_;

    fused_pool_kernel<<<B_ * L_ * 2, 256, 0, stream>>>(
        x, adj, conv_w, conv_b, re_param, pooled_x, pooled_adj);
}